// Round 8
// baseline (251.130 us; speedup 1.0000x reference)
//
#include <hip/hip_runtime.h>
#include <hip/hip_bf16.h>

// Problem constants (B=2, L=2048, D=1024, H=8, pd=128).
#define L_SEQ   2048
#define D_MODEL 1024
#define B_SZ    2
#define LP      (L_SEQ + 192)   // padded sequence length: 96 front + 96 back
#define PADF    96

typedef __attribute__((ext_vector_type(8))) short bf16x8;
typedef __attribute__((ext_vector_type(4))) float f32x4;

// async global->LDS, 16B per lane (global_load_lds_dwordx4)
__device__ __forceinline__ void gll16(const void* g, void* l) {
    __builtin_amdgcn_global_load_lds(
        (const __attribute__((address_space(1))) unsigned int*)(g),
        (__attribute__((address_space(3))) unsigned int*)(l),
        16, 0, 0);
}

__device__ __forceinline__ ushort bf16_hi(float x) {
    __hip_bfloat16 h = __float2bfloat16(x);
    return *reinterpret_cast<ushort*>(&h);
}
__device__ __forceinline__ float bf16_back(ushort u) {
    __hip_bfloat16 h = *reinterpret_cast<__hip_bfloat16*>(&u);
    return __bfloat162float(h);
}

// ---------------------------------------------------------------------------
// init_ctr: zero the grid-barrier counter (separate launch -> no init race).
__global__ __launch_bounds__(64) void init_ctr(int* __restrict__ ctr)
{
    if (threadIdx.x < 16) ctr[threadIdx.x] = 0;
}

// Grid barrier for exactly-resident grids (256 blocks x 1/CU).
// Producer: each wave's stores drained at __syncthreads (compiler vmcnt(0));
// thread0 __threadfence() (agent release: L2 writeback) then device atomicAdd.
// Consumer: agent-scope acquire spin-load (invalidates stale cached lines).
// Monotonic target per phase -> no counter reset needed.
__device__ __forceinline__ void grid_barrier(int* ctr, int target)
{
    __syncthreads();
    if (threadIdx.x == 0) {
        __threadfence();
        __hip_atomic_fetch_add(ctr, 1, __ATOMIC_ACQ_REL, __HIP_MEMORY_SCOPE_AGENT);
        int guard = 0;
        while (__hip_atomic_load(ctr, __ATOMIC_ACQUIRE, __HIP_MEMORY_SCOPE_AGENT) < target
               && guard < (1 << 22)) {            // bounded spin (~1.8s): hang -> fail, not wedge
            __builtin_amdgcn_s_sleep(16);
            ++guard;
        }
    }
    __syncthreads();
}

// ---------------------------------------------------------------------------
// phase_prep: grid-stride over 16B units: zero vpad pads (minus the reserved
// barrier-counter row b=1,rr=95 — never read by conv) + split values/w_in/
// w_out into bf16 hi/lo planes.
__device__ __forceinline__ void phase_prep(const float* __restrict__ values,
                                           const float* __restrict__ w_in,
                                           const float* __restrict__ w_out,
                                           ushort* __restrict__ Ph, ushort* __restrict__ Pl,
                                           ushort* __restrict__ Wh, ushort* __restrict__ Wl,
                                           ushort* __restrict__ W2h, ushort* __restrict__ W2l,
                                           float* __restrict__ vpad)
{
    const int NZ = 98304;                 // 4 regions * 96 rows * 256 float4
    const int NV = 1048576;               // values float4 units
    const int NW = 262144;                // per-weight float4 units
    const int TOT = NZ + NV + 2 * NW;
    for (int u = blockIdx.x * 512 + threadIdx.x; u < TOT; u += 256 * 512) {
        if (u < NZ) {
            const int r  = u / 24576;
            const int rr = (u - r * 24576) >> 8;
            const int c4 = u & 255;
            if (r == 3 && rr == 95) continue;          // reserved: grid-barrier ctr row
            const int b = r >> 1;
            const int row0 = (r & 1) ? (LP - 96) : 0;
            *(float4*)(vpad + (size_t)(b * LP + row0 + rr) * 1024 + c4 * 4) =
                make_float4(0.f, 0.f, 0.f, 0.f);
            continue;
        }
        int v = u - NZ;
        const float* src;
        ushort *oh, *ol;
        if (v < NV)           { src = values; oh = Ph;  ol = Pl;  }
        else if (v < NV + NW) { src = w_in;   oh = Wh;  ol = Wl;  v -= NV; }
        else                  { src = w_out;  oh = W2h; ol = W2l; v -= NV + NW; }
        const size_t i = (size_t)v * 4;
        float4 x = *(const float4*)(src + i);
        float f[4] = {x.x, x.y, x.z, x.w};
        ushort hb[4], lb[4];
        #pragma unroll
        for (int j = 0; j < 4; ++j) {
            hb[j] = bf16_hi(f[j]);
            lb[j] = bf16_hi(f[j] - bf16_back(hb[j]));
        }
        *(ushort4*)(oh + i) = make_ushort4(hb[0], hb[1], hb[2], hb[3]);
        *(ushort4*)(ol + i) = make_ushort4(lb[0], lb[1], lb[2], lb[3]);
    }
}

// ---------------------------------------------------------------------------
// phase_gemm: byte-identical R6 GEMM as a device function.
// C[M,N] = (Ah+Al)*(Bh+Bl)^T via 3 bf16 MFMA products, fp32 acc.
// Tile 128x128, BK=32, 8 waves (2m x 4n). 4-buf counted-vmcnt pipeline,
// WAITBAR(8). Column-slab XCD swizzle. k-chunk XOR swizzle (source-side).
template<int DO_PAD>
__device__ __forceinline__ void phase_gemm(ushort lds[4][4][4096],
                                           const ushort* __restrict__ Ah,
                                           const ushort* __restrict__ Al,
                                           const ushort* __restrict__ Bh,
                                           const ushort* __restrict__ Bl,
                                           float* __restrict__ C)
{
    const int tid = threadIdx.x;
    const int w   = tid >> 6;
    const int l   = tid & 63;

    const int bn  = (blockIdx.x & 7) * 128;          // one n-panel per XCD
    const int bm  = (blockIdx.x >> 3) * 128;

    const int srow   = tid >> 2;                          // 0..127
    const int schunk = (tid & 3) ^ ((tid >> 3) & 3);      // pre-swizzled source chunk
    const ushort* gAh = Ah + (size_t)(bm + srow) * 1024 + schunk * 8;
    const ushort* gAl = Al + (size_t)(bm + srow) * 1024 + schunk * 8;
    const ushort* gBh = Bh + (size_t)(bn + srow) * 1024 + schunk * 8;
    const ushort* gBl = Bl + (size_t)(bn + srow) * 1024 + schunk * 8;
    const int ldst = tid * 8;

    const int fr  = l & 15;
    const int fq  = l >> 4;
    const int swz = (fr >> 1) & 3;
    const int rdo = (fq ^ swz) << 3;
    const int wr  = w >> 2;
    const int wc  = w & 3;

    f32x4 acc[4][2];
    #pragma unroll
    for (int mi = 0; mi < 4; ++mi)
        #pragma unroll
        for (int ni = 0; ni < 2; ++ni) acc[mi][ni] = (f32x4){0.f, 0.f, 0.f, 0.f};

    #define STAGE(buf, kt)                                        \
        do {                                                      \
            const size_t ko_ = (size_t)(kt) * 32;                 \
            gll16(gAh + ko_, &lds[(buf)][0][ldst]);               \
            gll16(gAl + ko_, &lds[(buf)][1][ldst]);               \
            gll16(gBh + ko_, &lds[(buf)][2][ldst]);               \
            gll16(gBl + ko_, &lds[(buf)][3][ldst]);               \
        } while (0)

    #define WAITBAR(N) asm volatile("s_waitcnt vmcnt(" #N ")\n\ts_barrier" ::: "memory")

    #define COMPUTE(cur)                                                                   \
        do {                                                                               \
            bf16x8 ah[4], al[4];                                                           \
            _Pragma("unroll")                                                              \
            for (int mi = 0; mi < 4; ++mi) {                                               \
                const int row = wr * 64 + mi * 16 + fr;                                    \
                ah[mi] = *(const bf16x8*)&lds[(cur)][0][row * 32 + rdo];                   \
                al[mi] = *(const bf16x8*)&lds[(cur)][1][row * 32 + rdo];                   \
            }                                                                              \
            _Pragma("unroll")                                                              \
            for (int ni = 0; ni < 2; ++ni) {                                               \
                const int row = wc * 32 + ni * 16 + fr;                                    \
                bf16x8 bh = *(const bf16x8*)&lds[(cur)][2][row * 32 + rdo];                \
                bf16x8 bl = *(const bf16x8*)&lds[(cur)][3][row * 32 + rdo];                \
                _Pragma("unroll")                                                          \
                for (int mi = 0; mi < 4; ++mi)                                             \
                    acc[mi][ni] = __builtin_amdgcn_mfma_f32_16x16x32_bf16(ah[mi], bh, acc[mi][ni], 0, 0, 0); \
                _Pragma("unroll")                                                          \
                for (int mi = 0; mi < 4; ++mi)                                             \
                    acc[mi][ni] = __builtin_amdgcn_mfma_f32_16x16x32_bf16(al[mi], bh, acc[mi][ni], 0, 0, 0); \
                _Pragma("unroll")                                                          \
                for (int mi = 0; mi < 4; ++mi)                                             \
                    acc[mi][ni] = __builtin_amdgcn_mfma_f32_16x16x32_bf16(ah[mi], bl, acc[mi][ni], 0, 0, 0); \
            }                                                                              \
        } while (0)

    STAGE(0, 0);
    STAGE(1, 1);
    STAGE(2, 2);

    for (int kt = 0; kt < 29; ++kt) {
        WAITBAR(8);
        STAGE((kt + 3) & 3, kt + 3);
        COMPUTE(kt & 3);
    }
    WAITBAR(8); COMPUTE(1);   // kt=29
    WAITBAR(4); COMPUTE(2);   // kt=30
    WAITBAR(0); COMPUTE(3);   // kt=31

    #undef STAGE
    #undef WAITBAR
    #undef COMPUTE

    // epilogue: C/D layout col=lane&15, row=(lane>>4)*4+reg  [m89/m91]
    #pragma unroll
    for (int mi = 0; mi < 4; ++mi) {
        #pragma unroll
        for (int ni = 0; ni < 2; ++ni) {
            const int col = bn + wc * 32 + ni * 16 + fr;
            #pragma unroll
            for (int j = 0; j < 4; ++j) {
                const int m = bm + wr * 64 + mi * 16 + fq * 4 + j;
                const size_t row = DO_PAD ? ((size_t)(m >> 11) * LP + (m & (L_SEQ - 1)) + PADF)
                                          : (size_t)m;
                C[row * 1024 + col] = acc[mi][ni][j];
            }
        }
    }
}

// ---------------------------------------------------------------------------
// phase_conv: same algorithm as R6 conv, re-geometried to 512 threads.
// Block = 128 d-cols (one head) x 128 q-rows; stages 256 rows x 128 floats
// (128KB) once; thread: d=tid&127, q-slice (tid>>7)*32, 47-reg window.
__device__ __forceinline__ void phase_conv(float* xs /*[256*128]*/,
                                           float* wt /*[128]*/,
                                           const float* __restrict__ vpad,
                                           ushort* __restrict__ Oh,
                                           ushort* __restrict__ Ol)
{
    const int tid = threadIdx.x;
    const int blk = blockIdx.x;              // 0..255
    const int d0  = (blk & 7) * 128;
    const int q0  = ((blk >> 3) & 15) * 128;
    const int b   = blk >> 7;
    const int h   = blk & 7;                 // head = d0/128

    if (tid < 128) {
        const float sig = (float)(1 << (h & 3));   // std 1,2,4,8 ; offset = -std
        const float t = ((float)(tid - 71) + sig) / sig;
        wt[tid] = (0.39894228040143267794f / sig) * expf(-0.5f * t * t);
    }

    // stage rows [q0-71, q0+184] x [d0, d0+128)
    const float* src = vpad + ((size_t)b * LP + (PADF - 71) + q0) * 1024 + d0;
    #pragma unroll
    for (int p = 0; p < 16; ++p) {
        const int f   = p * 512 + tid;       // float4 index (256 rows * 32/row)
        const int row = f >> 5;
        const int c4  = (f & 31) * 4;
        gll16(src + (size_t)row * 1024 + c4, xs + (size_t)f * 4);
    }
    __syncthreads();                          // drains gll16 + wt visible

    const int d     = tid & 127;
    const int qbase = (tid >> 7) * 32;

    float acc[32];
    #pragma unroll
    for (int qq = 0; qq < 32; ++qq) acc[qq] = 0.f;

    #pragma unroll 1
    for (int c = 0; c < 8; ++c) {
        float xw[47];
        const float* xp = xs + (qbase + c * 16) * 128 + d;
        #pragma unroll
        for (int j = 0; j < 47; ++j) xw[j] = xp[j * 128];
        #pragma unroll
        for (int dd = 0; dd < 16; ++dd) {
            const float wv = wt[c * 16 + dd];
            #pragma unroll
            for (int qq = 0; qq < 32; ++qq)
                acc[qq] = fmaf(wv, xw[dd + qq], acc[qq]);
        }
    }

    ushort* oh = Oh + ((size_t)b * L_SEQ + q0 + qbase) * 1024 + d0 + d;
    ushort* ol = Ol + ((size_t)b * L_SEQ + q0 + qbase) * 1024 + d0 + d;
    #pragma unroll
    for (int qq = 0; qq < 32; ++qq) {
        const ushort hv = bf16_hi(acc[qq]);
        oh[(size_t)qq * 1024] = hv;
        ol[(size_t)qq * 1024] = bf16_hi(acc[qq] - bf16_back(hv));
    }
}

// ---------------------------------------------------------------------------
// mega: persistent fused kernel. 256 blocks x 512 threads, 1 block/CU
// (129KB LDS) -> all blocks co-resident -> software grid barriers valid.
__global__ __launch_bounds__(512, 1) void mega(const float* __restrict__ values,
                                               const float* __restrict__ w_in,
                                               const float* __restrict__ w_out,
                                               float* __restrict__ out,
                                               float* __restrict__ vpad,
                                               ushort* __restrict__ Ph, ushort* __restrict__ Pl,
                                               ushort* __restrict__ Wh, ushort* __restrict__ Wl,
                                               ushort* __restrict__ W2h, ushort* __restrict__ W2l,
                                               int* __restrict__ ctr)
{
    union SharedU {
        ushort g[4][4][4096];    // gemm: 4 bufs x 4 planes x 8KB = 128KB
        float  xs[256 * 128];    // conv: 256 rows x 128 floats = 128KB
    };
    __shared__ SharedU sh;
    __shared__ float wt[128];

    phase_prep(values, w_in, w_out, Ph, Pl, Wh, Wl, W2h, W2l, vpad);
    grid_barrier(ctr, 256);
    phase_gemm<1>(sh.g, Ph, Pl, Wh, Wl, vpad);
    grid_barrier(ctr, 512);
    phase_conv(sh.xs, wt, vpad, Ph, Pl);
    grid_barrier(ctr, 768);
    phase_gemm<0>(sh.g, Ph, Pl, W2h, W2l, out);
}

// ---------------------------------------------------------------------------
extern "C" void kernel_launch(void* const* d_in, const int* in_sizes, int n_in,
                              void* d_out, int out_size, void* d_ws, size_t ws_size,
                              hipStream_t stream)
{
    const float* values = (const float*)d_in[0];   // [B,L,D]
    const float* w_in   = (const float*)d_in[1];   // [D,D]
    const float* w_out  = (const float*)d_in[2];   // [D,D]
    float* out = (float*)d_out;                    // [B,L,D]

    // workspace layout (43.5 MB total, unchanged)
    float*  vpad = (float*)d_ws;                                  // [B][LP][D] fp32
    ushort* Ph  = (ushort*)(vpad + (size_t)B_SZ * LP * D_MODEL);  // [4096][1024] bf16 hi
    ushort* Pl  = Ph  + (size_t)4096 * 1024;                      // lo
    ushort* Wh  = Pl  + (size_t)4096 * 1024;                      // w_in hi
    ushort* Wl  = Wh  + (size_t)1024 * 1024;                      // w_in lo
    ushort* W2h = Wl  + (size_t)1024 * 1024;                      // w_out hi
    ushort* W2l = W2h + (size_t)1024 * 1024;                      // w_out lo
    // barrier counter: reserved vpad row (b=1, back-pad row 95) — zeroed by
    // init_ctr, skipped by prep's zeroing, never read by conv.
    int* ctr = (int*)(vpad + (size_t)(2 * LP - 1) * 1024);

    init_ctr<<<dim3(1), dim3(64), 0, stream>>>(ctr);
    mega<<<dim3(256), dim3(512), 0, stream>>>(values, w_in, w_out, out,
                                              vpad, Ph, Pl, Wh, Wl, W2h, W2l, ctr);
}

// Round 9
// 161.839 us; speedup vs baseline: 1.5517x; 1.5517x over previous
//
#include <hip/hip_runtime.h>
#include <hip/hip_bf16.h>

// Problem constants (B=2, L=2048, D=1024, H=8, pd=128).
#define L_SEQ   2048
#define D_MODEL 1024
#define B_SZ    2
#define LP      (L_SEQ + 192)   // padded sequence length: 96 front + 96 back
#define PADF    96

typedef __attribute__((ext_vector_type(8))) short bf16x8;
typedef __attribute__((ext_vector_type(4))) float f32x4;

// async global->LDS, 16B per lane (global_load_lds_dwordx4)
__device__ __forceinline__ void gll16(const void* g, void* l) {
    __builtin_amdgcn_global_load_lds(
        (const __attribute__((address_space(1))) unsigned int*)(g),
        (__attribute__((address_space(3))) unsigned int*)(l),
        16, 0, 0);
}

__device__ __forceinline__ ushort bf16_hi(float x) {
    __hip_bfloat16 h = __float2bfloat16(x);
    return *reinterpret_cast<ushort*>(&h);
}
__device__ __forceinline__ float bf16_back(ushort u) {
    __hip_bfloat16 h = *reinterpret_cast<__hip_bfloat16*>(&u);
    return __bfloat162float(h);
}

// ---------------------------------------------------------------------------
// prep: one launch: (a) zero vpad pad rows [384 blocks], (b) split values
// [4096 blocks], (c) split w_in [1024], (d) split w_out [1024].
__global__ __launch_bounds__(256) void prep(const float* __restrict__ values,
                                            const float* __restrict__ w_in,
                                            const float* __restrict__ w_out,
                                            ushort* __restrict__ Ph, ushort* __restrict__ Pl,
                                            ushort* __restrict__ Wh, ushort* __restrict__ Wl,
                                            ushort* __restrict__ W2h, ushort* __restrict__ W2l,
                                            float* __restrict__ vpad)
{
    int blk = blockIdx.x;
    if (blk < 384) {                               // zero the 4 pad regions
        const int r  = blk / 96;
        const int rr = blk % 96;
        const int b  = r >> 1;
        const int row0 = (r & 1) ? (LP - 96) : 0;
        size_t off = ((size_t)b * LP + row0 + rr) * D_MODEL + threadIdx.x * 4;
        *(float4*)(vpad + off) = make_float4(0.f, 0.f, 0.f, 0.f);
        return;
    }
    blk -= 384;
    const float* src;
    ushort *oh, *ol;
    if (blk < 4096)      { src = values; oh = Ph;  ol = Pl;  }
    else if (blk < 5120) { src = w_in;   oh = Wh;  ol = Wl;  blk -= 4096; }
    else                 { src = w_out;  oh = W2h; ol = W2l; blk -= 5120; }

    const size_t i = ((size_t)blk * 256 + threadIdx.x) * 4;
    float4 v = *(const float4*)(src + i);
    float f[4] = {v.x, v.y, v.z, v.w};
    ushort hb[4], lb[4];
    #pragma unroll
    for (int j = 0; j < 4; ++j) {
        hb[j] = bf16_hi(f[j]);
        lb[j] = bf16_hi(f[j] - bf16_back(hb[j]));
    }
    *(ushort4*)(oh + i) = make_ushort4(hb[0], hb[1], hb[2], hb[3]);
    *(ushort4*)(ol + i) = make_ushort4(lb[0], lb[1], lb[2], lb[3]);
}

// ---------------------------------------------------------------------------
// gemm_split: C[M,N] = (Ah+Al)*(Bh+Bl)^T via 3 bf16 MFMA products, fp32 acc.
// M=4096, N=K=1024. Tile 128x128, BK=32, 256 threads = 4 waves (2m x 2n),
// wave-tile 64x64 (acc[4][4]).
// WHY 4 waves: LDS-read traffic = sum of per-wave operand slices. At 64x32
// wave-tiles (R6) that was 96KB/CU/K-step vs 233 cyc of MFMA -> LDS-bound 5x
// (R8 mega profile: MFMA busy only ~20us of ~80us gemm time). 64x64 wave
// tiles cut traffic to 64KB/K-step (16KB/wave: Ah+Al 8KB, Bh+Bl 8KB) with
// identical MFMA work -> LDS floor ~770 cyc/K-step.
// T4 counted-vmcnt pipeline: 4 LDS bufs (4 x 32KB = 128KB), 8 loads/tile,
// WAITBAR(16) steady state (2 younger tiles in flight). Column-slab XCD
// swizzle (grid 256: bn=(blk&7)*128 -> one n-panel per XCD, B slice L2-
// resident). Bank-conflict fix: k-chunk XOR swizzle on global SOURCE +
// same involution on ds_read (verified: SQ_LDS_BANK_CONFLICT=0).
// DO_PAD=1 remaps output row m -> vpad row (b*LP + (m&2047) + PADF).
template<int DO_PAD>
__global__ __launch_bounds__(256) void gemm_split(const ushort* __restrict__ Ah,
                                                  const ushort* __restrict__ Al,
                                                  const ushort* __restrict__ Bh,
                                                  const ushort* __restrict__ Bl,
                                                  float* __restrict__ C)
{
    // [buf][plane][128 rows * 32 k]  plane: 0=Ah 1=Al 2=Bh 3=Bl
    __shared__ __align__(16) ushort lds[4][4][4096];

    const int tid = threadIdx.x;
    const int w   = tid >> 6;      // wave 0..3
    const int l   = tid & 63;

    const int bn  = (blockIdx.x & 7) * 128;          // one n-panel per XCD
    const int bm  = (blockIdx.x >> 3) * 128;         // 32 m-panels

    // --- staging: 256 threads x 16B = 4KB per issue; 8 issues per K-tile ---
    const int srow   = tid >> 2;                          // 0..63
    const int schunk = (tid & 3) ^ ((tid >> 3) & 3);      // pre-swizzled source chunk
    const ushort* gAh0 = Ah + (size_t)(bm + srow) * 1024 + schunk * 8;
    const ushort* gAh1 = gAh0 + (size_t)64 * 1024;
    const ushort* gAl0 = Al + (size_t)(bm + srow) * 1024 + schunk * 8;
    const ushort* gAl1 = gAl0 + (size_t)64 * 1024;
    const ushort* gBh0 = Bh + (size_t)(bn + srow) * 1024 + schunk * 8;
    const ushort* gBh1 = gBh0 + (size_t)64 * 1024;
    const ushort* gBl0 = Bl + (size_t)(bn + srow) * 1024 + schunk * 8;
    const ushort* gBl1 = gBl0 + (size_t)64 * 1024;
    const int ldst = tid * 8;                             // linear LDS dest (ushort)

    // --- fragment read params ---
    const int fr  = l & 15;                // row within 16x16 fragment
    const int fq  = l >> 4;                // k-chunk 0..3
    const int swz = (fr >> 1) & 3;         // row-XOR for bank spread
    const int rdo = (fq ^ swz) << 3;       // element offset of swizzled chunk
    const int wr  = w >> 1;                // 0..1 -> m offset wr*64
    const int wc  = w & 1;                 // 0..1 -> n offset wc*64

    f32x4 acc[4][4];
    #pragma unroll
    for (int mi = 0; mi < 4; ++mi)
        #pragma unroll
        for (int ni = 0; ni < 4; ++ni) acc[mi][ni] = (f32x4){0.f, 0.f, 0.f, 0.f};

    #define STAGE(buf, kt)                                        \
        do {                                                      \
            const size_t ko_ = (size_t)(kt) * 32;                 \
            gll16(gAh0 + ko_, &lds[(buf)][0][ldst]);              \
            gll16(gAh1 + ko_, &lds[(buf)][0][2048 + ldst]);       \
            gll16(gAl0 + ko_, &lds[(buf)][1][ldst]);              \
            gll16(gAl1 + ko_, &lds[(buf)][1][2048 + ldst]);       \
            gll16(gBh0 + ko_, &lds[(buf)][2][ldst]);              \
            gll16(gBh1 + ko_, &lds[(buf)][2][2048 + ldst]);       \
            gll16(gBl0 + ko_, &lds[(buf)][3][ldst]);              \
            gll16(gBl1 + ko_, &lds[(buf)][3][2048 + ldst]);       \
        } while (0)

    // WAITBAR(N): my tile-(kt) loads retired (N younger stay in flight),
    // then barrier -> ALL waves' tile-(kt) loads are in LDS.
    #define WAITBAR(N) asm volatile("s_waitcnt vmcnt(" #N ")\n\ts_barrier" ::: "memory")

    #define COMPUTE(cur)                                                                   \
        do {                                                                               \
            bf16x8 ah[4], al[4];                                                           \
            _Pragma("unroll")                                                              \
            for (int mi = 0; mi < 4; ++mi) {                                               \
                const int row = wr * 64 + mi * 16 + fr;                                    \
                ah[mi] = *(const bf16x8*)&lds[(cur)][0][row * 32 + rdo];                   \
                al[mi] = *(const bf16x8*)&lds[(cur)][1][row * 32 + rdo];                   \
            }                                                                              \
            _Pragma("unroll")                                                              \
            for (int ni = 0; ni < 4; ++ni) {                                               \
                const int row = wc * 64 + ni * 16 + fr;                                    \
                bf16x8 bh = *(const bf16x8*)&lds[(cur)][2][row * 32 + rdo];                \
                bf16x8 bl = *(const bf16x8*)&lds[(cur)][3][row * 32 + rdo];                \
                _Pragma("unroll")                                                          \
                for (int mi = 0; mi < 4; ++mi)                                             \
                    acc[mi][ni] = __builtin_amdgcn_mfma_f32_16x16x32_bf16(ah[mi], bh, acc[mi][ni], 0, 0, 0); \
                _Pragma("unroll")                                                          \
                for (int mi = 0; mi < 4; ++mi)                                             \
                    acc[mi][ni] = __builtin_amdgcn_mfma_f32_16x16x32_bf16(al[mi], bh, acc[mi][ni], 0, 0, 0); \
                _Pragma("unroll")                                                          \
                for (int mi = 0; mi < 4; ++mi)                                             \
                    acc[mi][ni] = __builtin_amdgcn_mfma_f32_16x16x32_bf16(ah[mi], bl, acc[mi][ni], 0, 0, 0); \
            }                                                                              \
        } while (0)

    STAGE(0, 0);
    STAGE(1, 1);
    STAGE(2, 2);

    for (int kt = 0; kt < 29; ++kt) {
        WAITBAR(16);
        STAGE((kt + 3) & 3, kt + 3);
        COMPUTE(kt & 3);
    }
    WAITBAR(16); COMPUTE(1);   // kt=29
    WAITBAR(8);  COMPUTE(2);   // kt=30
    WAITBAR(0);  COMPUTE(3);   // kt=31

    #undef STAGE
    #undef WAITBAR
    #undef COMPUTE

    // epilogue: C/D layout col=lane&15, row=(lane>>4)*4+reg  [m89/m91]
    #pragma unroll
    for (int mi = 0; mi < 4; ++mi) {
        #pragma unroll
        for (int ni = 0; ni < 4; ++ni) {
            const int col = bn + wc * 64 + ni * 16 + fr;
            #pragma unroll
            for (int j = 0; j < 4; ++j) {
                const int m = bm + wr * 64 + mi * 16 + fq * 4 + j;
                const size_t row = DO_PAD ? ((size_t)(m >> 11) * LP + (m & (L_SEQ - 1)) + PADF)
                                          : (size_t)m;
                C[row * 1024 + col] = acc[mi][ni][j];
            }
        }
    }
}

// ---------------------------------------------------------------------------
// gauss_conv_split: att[b,q,d] = sum_{delta=-71..56} w[h][delta]*vpad[b,q+delta,d]
// (delta=-72 term <= 5e-16, dropped). Block = 64 d-cols x 128 q-rows; stages
// 256 rows x 64 floats (64KB) in LDS once; each thread owns one d-column and
// 32 q-accumulators, sliding a 47-register window per 16-delta chunk.
// Emits bf16 hi/lo planes directly.
__global__ __launch_bounds__(256) void gauss_conv_split(const float* __restrict__ vpad,
                                                        ushort* __restrict__ Oh,
                                                        ushort* __restrict__ Ol)
{
    __shared__ __align__(16) float xs[256 * 64];   // [row][d] 64KB
    __shared__ float wt[128];                      // delta = j - 71

    const int tid = threadIdx.x;
    const int d0  = blockIdx.x * 64;
    const int q0  = blockIdx.y * 128;
    const int b   = blockIdx.z;
    const int h   = blockIdx.x >> 1;               // 64-wide d block => single head

    if (tid < 128) {
        const float sig = (float)(1 << (h & 3));   // std 1,2,4,8 ; offset = -std
        const float t = ((float)(tid - 71) + sig) / sig;
        wt[tid] = (0.39894228040143267794f / sig) * expf(-0.5f * t * t);
    }

    // stage rows [q0-71, q0+184] x [d0, d0+64)
    const float* src = vpad + ((size_t)b * LP + (PADF - 71) + q0) * 1024 + d0;
    #pragma unroll
    for (int p = 0; p < 16; ++p) {
        const int f   = p * 256 + tid;             // float4 index
        const int row = f >> 4;
        const int c4  = (f & 15) * 4;
        gll16(src + (size_t)row * 1024 + c4, &xs[f * 4]);
    }
    __syncthreads();

    const int d     = tid & 63;
    const int qbase = (tid >> 6) * 32;

    float acc[32];
    #pragma unroll
    for (int qq = 0; qq < 32; ++qq) acc[qq] = 0.f;

    #pragma unroll 1
    for (int c = 0; c < 8; ++c) {
        float xw[47];
        const float* xp = &xs[(qbase + c * 16) * 64 + d];
        #pragma unroll
        for (int j = 0; j < 47; ++j) xw[j] = xp[j * 64];
        #pragma unroll
        for (int dd = 0; dd < 16; ++dd) {
            const float wv = wt[c * 16 + dd];      // block-uniform broadcast
            #pragma unroll
            for (int qq = 0; qq < 32; ++qq)
                acc[qq] = fmaf(wv, xw[dd + qq], acc[qq]);
        }
    }

    ushort* oh = Oh + ((size_t)b * L_SEQ + q0 + qbase) * 1024 + d0 + d;
    ushort* ol = Ol + ((size_t)b * L_SEQ + q0 + qbase) * 1024 + d0 + d;
    #pragma unroll
    for (int qq = 0; qq < 32; ++qq) {
        const ushort hv = bf16_hi(acc[qq]);
        oh[(size_t)qq * 1024] = hv;
        ol[(size_t)qq * 1024] = bf16_hi(acc[qq] - bf16_back(hv));
    }
}

// ---------------------------------------------------------------------------
extern "C" void kernel_launch(void* const* d_in, const int* in_sizes, int n_in,
                              void* d_out, int out_size, void* d_ws, size_t ws_size,
                              hipStream_t stream)
{
    const float* values = (const float*)d_in[0];   // [B,L,D]
    const float* w_in   = (const float*)d_in[1];   // [D,D]
    const float* w_out  = (const float*)d_in[2];   // [D,D]
    float* out = (float*)d_out;                    // [B,L,D]

    // workspace layout (43.5 MB total)
    float*  vpad = (float*)d_ws;                                  // [B][LP][D] fp32
    ushort* Ph  = (ushort*)(vpad + (size_t)B_SZ * LP * D_MODEL);  // [4096][1024] bf16 hi
    ushort* Pl  = Ph  + (size_t)4096 * 1024;                      // lo
    ushort* Wh  = Pl  + (size_t)4096 * 1024;                      // w_in hi
    ushort* Wl  = Wh  + (size_t)1024 * 1024;                      // w_in lo
    ushort* W2h = Wl  + (size_t)1024 * 1024;                      // w_out hi
    ushort* W2l = W2h + (size_t)1024 * 1024;                      // w_out lo

    // 1) prep: zero pads + split values/w_in/w_out into bf16 hi/lo planes
    prep<<<dim3(384 + 4096 + 1024 + 1024), dim3(256), 0, stream>>>(
        values, w_in, w_out, Ph, Pl, Wh, Wl, W2h, W2l, vpad);

    // 2) v = values @ w_in^T  (into padded fp32 buffer)
    gemm_split<1><<<dim3(256), dim3(256), 0, stream>>>(Ph, Pl, Wh, Wl, vpad);

    // 3) Gaussian conv -> att, emitted as bf16 hi/lo planes (reuses Ph/Pl)
    dim3 cgrid(D_MODEL / 64, L_SEQ / 128, B_SZ);   // 16 x 16 x 2 = 512 blocks
    gauss_conv_split<<<cgrid, dim3(256), 0, stream>>>(vpad, Ph, Pl);

    // 4) out = att @ w_out^T
    gemm_split<0><<<dim3(256), dim3(256), 0, stream>>>(Ph, Pl, W2h, W2l, out);
}

// Round 10
// 160.078 us; speedup vs baseline: 1.5688x; 1.0110x over previous
//
#include <hip/hip_runtime.h>
#include <hip/hip_bf16.h>

// Problem constants (B=2, L=2048, D=1024, H=8, pd=128).
#define L_SEQ   2048
#define D_MODEL 1024
#define B_SZ    2
#define LP      (L_SEQ + 192)   // padded sequence length: 96 front + 96 back
#define PADF    96

typedef __attribute__((ext_vector_type(8))) short bf16x8;
typedef __attribute__((ext_vector_type(4))) float f32x4;

// async global->LDS, 16B per lane (global_load_lds_dwordx4)
__device__ __forceinline__ void gll16(const void* g, void* l) {
    __builtin_amdgcn_global_load_lds(
        (const __attribute__((address_space(1))) unsigned int*)(g),
        (__attribute__((address_space(3))) unsigned int*)(l),
        16, 0, 0);
}

__device__ __forceinline__ ushort bf16_hi(float x) {
    __hip_bfloat16 h = __float2bfloat16(x);
    return *reinterpret_cast<ushort*>(&h);
}
__device__ __forceinline__ float bf16_back(ushort u) {
    __hip_bfloat16 h = *reinterpret_cast<__hip_bfloat16*>(&u);
    return __bfloat162float(h);
}

// ---------------------------------------------------------------------------
// prep: one launch: (a) zero vpad pad rows [384 blocks], (b) split values
// [4096 blocks], (c) split w_in [1024], (d) split w_out [1024].
__global__ __launch_bounds__(256) void prep(const float* __restrict__ values,
                                            const float* __restrict__ w_in,
                                            const float* __restrict__ w_out,
                                            ushort* __restrict__ Ph, ushort* __restrict__ Pl,
                                            ushort* __restrict__ Wh, ushort* __restrict__ Wl,
                                            ushort* __restrict__ W2h, ushort* __restrict__ W2l,
                                            float* __restrict__ vpad)
{
    int blk = blockIdx.x;
    if (blk < 384) {                               // zero the 4 pad regions
        const int r  = blk / 96;
        const int rr = blk % 96;
        const int b  = r >> 1;
        const int row0 = (r & 1) ? (LP - 96) : 0;
        size_t off = ((size_t)b * LP + row0 + rr) * D_MODEL + threadIdx.x * 4;
        *(float4*)(vpad + off) = make_float4(0.f, 0.f, 0.f, 0.f);
        return;
    }
    blk -= 384;
    const float* src;
    ushort *oh, *ol;
    if (blk < 4096)      { src = values; oh = Ph;  ol = Pl;  }
    else if (blk < 5120) { src = w_in;   oh = Wh;  ol = Wl;  blk -= 4096; }
    else                 { src = w_out;  oh = W2h; ol = W2l; blk -= 5120; }

    const size_t i = ((size_t)blk * 256 + threadIdx.x) * 4;
    float4 v = *(const float4*)(src + i);
    float f[4] = {v.x, v.y, v.z, v.w};
    ushort hb[4], lb[4];
    #pragma unroll
    for (int j = 0; j < 4; ++j) {
        hb[j] = bf16_hi(f[j]);
        lb[j] = bf16_hi(f[j] - bf16_back(hb[j]));
    }
    *(ushort4*)(oh + i) = make_ushort4(hb[0], hb[1], hb[2], hb[3]);
    *(ushort4*)(ol + i) = make_ushort4(lb[0], lb[1], lb[2], lb[3]);
}

// ---------------------------------------------------------------------------
// gemm_split: C[M,N] = (Ah+Al)*(Bh+Bl)^T via 3 bf16 MFMA products, fp32 acc.
// M=4096, N=K=1024. Tile 128x128, BK=32, 512 threads = 8 waves (2m x 4n),
// wave-tile 64x32. 4-buf counted-vmcnt pipeline (WAITBAR(8), tile kt+3
// staged during step kt). R10 change: each K-step split into TWO PHASES by
// n-half (m201/T3 cadence, 4 barriers per 32k = 1 per 8k):
//   ph1: ds_read A-frags + B-half0 (10) || gll16 A-planes(t+3) | bar |
//        setprio(1) 12 MFMA setprio(0) | bar
//   ph2: ds_read B-half1 (2) || gll16 B-planes(t+3) | bar |
//        setprio(1) 12 MFMA setprio(0) | bar
// Rationale: at 1 block/CU nothing is saturated (MFMA 26%, LDS ~40%) —
// the single coarse WAITBAR per step convoys all 8 waves. Fine phases give
// the SIMD's 2 waves alternating read-issue/MFMA roles; T5 setprio pays
// only on phase-split structures (m218b/m190).
// DO_PAD=1 remaps output row m -> vpad row (b*LP + (m&2047) + PADF).
template<int DO_PAD>
__global__ __launch_bounds__(512) void gemm_split(const ushort* __restrict__ Ah,
                                                  const ushort* __restrict__ Al,
                                                  const ushort* __restrict__ Bh,
                                                  const ushort* __restrict__ Bl,
                                                  float* __restrict__ C)
{
    // [buf][plane][128 rows * 32 k]  plane: 0=Ah 1=Al 2=Bh 3=Bl
    __shared__ __align__(16) ushort lds[4][4][4096];

    const int tid = threadIdx.x;
    const int w   = tid >> 6;
    const int l   = tid & 63;

    // Column-slab XCD swizzle: xcd = blk&7 owns one n-panel (B L2-resident).
    const int bn  = (blockIdx.x & 7) * 128;
    const int bm  = (blockIdx.x >> 3) * 128;

    // --- staging: 512 threads x 16B = 8KB = one full plane per issue ---
    const int srow   = tid >> 2;                          // 0..127
    const int schunk = (tid & 3) ^ ((tid >> 3) & 3);      // pre-swizzled source chunk
    const ushort* gAh = Ah + (size_t)(bm + srow) * 1024 + schunk * 8;
    const ushort* gAl = Al + (size_t)(bm + srow) * 1024 + schunk * 8;
    const ushort* gBh = Bh + (size_t)(bn + srow) * 1024 + schunk * 8;
    const ushort* gBl = Bl + (size_t)(bn + srow) * 1024 + schunk * 8;
    const int ldst = tid * 8;                             // linear LDS dest (ushort)

    // --- fragment read params ---
    const int fr  = l & 15;                // row within 16x16 fragment
    const int fq  = l >> 4;                // k-chunk 0..3
    const int swz = (fr >> 1) & 3;         // chunk XOR (matches source swizzle)
    const int rdo = (fq ^ swz) << 3;       // element offset of swizzled chunk
    const int wr  = w >> 2;                // 0..1 -> m offset wr*64
    const int wc  = w & 3;                 // 0..3 -> n offset wc*32

    f32x4 acc[4][2];
    #pragma unroll
    for (int mi = 0; mi < 4; ++mi)
        #pragma unroll
        for (int ni = 0; ni < 2; ++ni) acc[mi][ni] = (f32x4){0.f, 0.f, 0.f, 0.f};

    #define STAGE(buf, kt)                                        \
        do {                                                      \
            const size_t ko_ = (size_t)(kt) * 32;                 \
            gll16(gAh + ko_, &lds[(buf)][0][ldst]);               \
            gll16(gAl + ko_, &lds[(buf)][1][ldst]);               \
            gll16(gBh + ko_, &lds[(buf)][2][ldst]);               \
            gll16(gBl + ko_, &lds[(buf)][3][ldst]);               \
        } while (0)

    // WAITBAR(N): my tile-(kt) loads retired (N younger in flight), then
    // barrier -> ALL waves' tile-(kt) loads are in LDS.
    #define WAITBAR(N) asm volatile("s_waitcnt vmcnt(" #N ")\n\ts_barrier" ::: "memory")
    #define BAR() __builtin_amdgcn_s_barrier()

    // Two-phase K-step. DO_STG in {0,1}: stage tile kt+3 while computing.
    #define STEP(cur, DO_STG, kt3)                                                         \
        do {                                                                               \
            bf16x8 ah[4], al[4];                                                           \
            _Pragma("unroll")                                                              \
            for (int mi = 0; mi < 4; ++mi) {                                               \
                const int row = wr * 64 + mi * 16 + fr;                                    \
                ah[mi] = *(const bf16x8*)&lds[(cur)][0][row * 32 + rdo];                   \
                al[mi] = *(const bf16x8*)&lds[(cur)][1][row * 32 + rdo];                   \
            }                                                                              \
            const int rowb0 = wc * 32 + fr;                                                \
            bf16x8 bh0 = *(const bf16x8*)&lds[(cur)][2][rowb0 * 32 + rdo];                 \
            bf16x8 bl0 = *(const bf16x8*)&lds[(cur)][3][rowb0 * 32 + rdo];                 \
            if (DO_STG) {                                                                  \
                const size_t ko_ = (size_t)(kt3) * 32;                                     \
                gll16(gAh + ko_, &lds[((cur) + 3) & 3][0][ldst]);                          \
                gll16(gAl + ko_, &lds[((cur) + 3) & 3][1][ldst]);                          \
            }                                                                              \
            BAR();                                                                         \
            __builtin_amdgcn_s_setprio(1);                                                 \
            _Pragma("unroll")                                                              \
            for (int mi = 0; mi < 4; ++mi)                                                 \
                acc[mi][0] = __builtin_amdgcn_mfma_f32_16x16x32_bf16(ah[mi], bh0, acc[mi][0], 0, 0, 0); \
            _Pragma("unroll")                                                              \
            for (int mi = 0; mi < 4; ++mi)                                                 \
                acc[mi][0] = __builtin_amdgcn_mfma_f32_16x16x32_bf16(al[mi], bh0, acc[mi][0], 0, 0, 0); \
            _Pragma("unroll")                                                              \
            for (int mi = 0; mi < 4; ++mi)                                                 \
                acc[mi][0] = __builtin_amdgcn_mfma_f32_16x16x32_bf16(ah[mi], bl0, acc[mi][0], 0, 0, 0); \
            __builtin_amdgcn_s_setprio(0);                                                 \
            BAR();                                                                         \
            const int rowb1 = wc * 32 + 16 + fr;                                           \
            bf16x8 bh1 = *(const bf16x8*)&lds[(cur)][2][rowb1 * 32 + rdo];                 \
            bf16x8 bl1 = *(const bf16x8*)&lds[(cur)][3][rowb1 * 32 + rdo];                 \
            if (DO_STG) {                                                                  \
                const size_t ko_ = (size_t)(kt3) * 32;                                     \
                gll16(gBh + ko_, &lds[((cur) + 3) & 3][2][ldst]);                          \
                gll16(gBl + ko_, &lds[((cur) + 3) & 3][3][ldst]);                          \
            }                                                                              \
            BAR();                                                                         \
            __builtin_amdgcn_s_setprio(1);                                                 \
            _Pragma("unroll")                                                              \
            for (int mi = 0; mi < 4; ++mi)                                                 \
                acc[mi][1] = __builtin_amdgcn_mfma_f32_16x16x32_bf16(ah[mi], bh1, acc[mi][1], 0, 0, 0); \
            _Pragma("unroll")                                                              \
            for (int mi = 0; mi < 4; ++mi)                                                 \
                acc[mi][1] = __builtin_amdgcn_mfma_f32_16x16x32_bf16(al[mi], bh1, acc[mi][1], 0, 0, 0); \
            _Pragma("unroll")                                                              \
            for (int mi = 0; mi < 4; ++mi)                                                 \
                acc[mi][1] = __builtin_amdgcn_mfma_f32_16x16x32_bf16(ah[mi], bl1, acc[mi][1], 0, 0, 0); \
            __builtin_amdgcn_s_setprio(0);                                                 \
            BAR();                                                                         \
        } while (0)

    STAGE(0, 0);
    STAGE(1, 1);
    STAGE(2, 2);

    for (int kt = 0; kt < 29; ++kt) {
        WAITBAR(8);
        STEP(kt & 3, 1, kt + 3);
    }
    WAITBAR(8); STEP(1, 0, 0);   // kt=29 (tiles 30,31 in flight)
    WAITBAR(4); STEP(2, 0, 0);   // kt=30
    WAITBAR(0); STEP(3, 0, 0);   // kt=31

    #undef STAGE
    #undef WAITBAR
    #undef BAR
    #undef STEP

    // epilogue: C/D layout col=lane&15, row=(lane>>4)*4+reg  [m89/m91]
    #pragma unroll
    for (int mi = 0; mi < 4; ++mi) {
        #pragma unroll
        for (int ni = 0; ni < 2; ++ni) {
            const int col = bn + wc * 32 + ni * 16 + fr;
            #pragma unroll
            for (int j = 0; j < 4; ++j) {
                const int m = bm + wr * 64 + mi * 16 + fq * 4 + j;
                const size_t row = DO_PAD ? ((size_t)(m >> 11) * LP + (m & (L_SEQ - 1)) + PADF)
                                          : (size_t)m;
                C[row * 1024 + col] = acc[mi][ni][j];
            }
        }
    }
}

// ---------------------------------------------------------------------------
// gauss_conv_split: att[b,q,d] = sum_{delta=-71..56} w[h][delta]*vpad[b,q+delta,d]
// (delta=-72 term <= 5e-16, dropped). Block = 64 d-cols x 128 q-rows; stages
// 256 rows x 64 floats (64KB) in LDS once; each thread owns one d-column and
// 32 q-accumulators, sliding a 47-register window per 16-delta chunk.
// Emits bf16 hi/lo planes directly. (Byte-identical to R6 for attribution.)
__global__ __launch_bounds__(256) void gauss_conv_split(const float* __restrict__ vpad,
                                                        ushort* __restrict__ Oh,
                                                        ushort* __restrict__ Ol)
{
    __shared__ __align__(16) float xs[256 * 64];   // [row][d] 64KB
    __shared__ float wt[128];                      // delta = j - 71

    const int tid = threadIdx.x;
    const int d0  = blockIdx.x * 64;
    const int q0  = blockIdx.y * 128;
    const int b   = blockIdx.z;
    const int h   = blockIdx.x >> 1;               // 64-wide d block => single head

    if (tid < 128) {
        const float sig = (float)(1 << (h & 3));   // std 1,2,4,8 ; offset = -std
        const float t = ((float)(tid - 71) + sig) / sig;
        wt[tid] = (0.39894228040143267794f / sig) * expf(-0.5f * t * t);
    }

    // stage rows [q0-71, q0+184] x [d0, d0+64)
    const float* src = vpad + ((size_t)b * LP + (PADF - 71) + q0) * 1024 + d0;
    #pragma unroll
    for (int p = 0; p < 16; ++p) {
        const int f   = p * 256 + tid;             // float4 index
        const int row = f >> 4;
        const int c4  = (f & 15) * 4;
        gll16(src + (size_t)row * 1024 + c4, &xs[f * 4]);
    }
    __syncthreads();

    const int d     = tid & 63;
    const int qbase = (tid >> 6) * 32;

    float acc[32];
    #pragma unroll
    for (int qq = 0; qq < 32; ++qq) acc[qq] = 0.f;

    #pragma unroll 1
    for (int c = 0; c < 8; ++c) {
        float xw[47];
        const float* xp = &xs[(qbase + c * 16) * 64 + d];
        #pragma unroll
        for (int j = 0; j < 47; ++j) xw[j] = xp[j * 64];
        #pragma unroll
        for (int dd = 0; dd < 16; ++dd) {
            const float wv = wt[c * 16 + dd];      // block-uniform broadcast
            #pragma unroll
            for (int qq = 0; qq < 32; ++qq)
                acc[qq] = fmaf(wv, xw[dd + qq], acc[qq]);
        }
    }

    ushort* oh = Oh + ((size_t)b * L_SEQ + q0 + qbase) * 1024 + d0 + d;
    ushort* ol = Ol + ((size_t)b * L_SEQ + q0 + qbase) * 1024 + d0 + d;
    #pragma unroll
    for (int qq = 0; qq < 32; ++qq) {
        const ushort hv = bf16_hi(acc[qq]);
        oh[(size_t)qq * 1024] = hv;
        ol[(size_t)qq * 1024] = bf16_hi(acc[qq] - bf16_back(hv));
    }
}

// ---------------------------------------------------------------------------
extern "C" void kernel_launch(void* const* d_in, const int* in_sizes, int n_in,
                              void* d_out, int out_size, void* d_ws, size_t ws_size,
                              hipStream_t stream)
{
    const float* values = (const float*)d_in[0];   // [B,L,D]
    const float* w_in   = (const float*)d_in[1];   // [D,D]
    const float* w_out  = (const float*)d_in[2];   // [D,D]
    float* out = (float*)d_out;                    // [B,L,D]

    // workspace layout (43.5 MB total)
    float*  vpad = (float*)d_ws;                                  // [B][LP][D] fp32
    ushort* Ph  = (ushort*)(vpad + (size_t)B_SZ * LP * D_MODEL);  // [4096][1024] bf16 hi
    ushort* Pl  = Ph  + (size_t)4096 * 1024;                      // lo
    ushort* Wh  = Pl  + (size_t)4096 * 1024;                      // w_in hi
    ushort* Wl  = Wh  + (size_t)1024 * 1024;                      // w_in lo
    ushort* W2h = Wl  + (size_t)1024 * 1024;                      // w_out hi
    ushort* W2l = W2h + (size_t)1024 * 1024;                      // w_out lo

    // 1) prep: zero pads + split values/w_in/w_out into bf16 hi/lo planes
    prep<<<dim3(384 + 4096 + 1024 + 1024), dim3(256), 0, stream>>>(
        values, w_in, w_out, Ph, Pl, Wh, Wl, W2h, W2l, vpad);

    // 2) v = values @ w_in^T  (into padded fp32 buffer)
    gemm_split<1><<<dim3(256), dim3(512), 0, stream>>>(Ph, Pl, Wh, Wl, vpad);

    // 3) Gaussian conv -> att, emitted as bf16 hi/lo planes (reuses Ph/Pl)
    dim3 cgrid(D_MODEL / 64, L_SEQ / 128, B_SZ);   // 16 x 16 x 2 = 512 blocks
    gauss_conv_split<<<cgrid, dim3(256), 0, stream>>>(vpad, Ph, Pl);

    // 4) out = att @ w_out^T
    gemm_split<0><<<dim3(256), dim3(512), 0, stream>>>(Ph, Pl, W2h, W2l, out);
}

// Round 11
// 131.312 us; speedup vs baseline: 1.9125x; 1.2191x over previous
//
#include <hip/hip_runtime.h>
#include <hip/hip_bf16.h>

// Problem constants (B=2, L=2048, D=1024, H=8, pd=128).
#define L_SEQ   2048
#define D_MODEL 1024
#define B_SZ    2
#define LP      (L_SEQ + 192)   // padded sequence length: 96 front + 96 back
#define PADF    96

typedef __attribute__((ext_vector_type(8))) short bf16x8;
typedef __attribute__((ext_vector_type(4))) float f32x4;

// async global->LDS, 16B per lane (global_load_lds_dwordx4)
__device__ __forceinline__ void gll16(const void* g, void* l) {
    __builtin_amdgcn_global_load_lds(
        (const __attribute__((address_space(1))) unsigned int*)(g),
        (__attribute__((address_space(3))) unsigned int*)(l),
        16, 0, 0);
}

__device__ __forceinline__ ushort bf16_hi(float x) {
    __hip_bfloat16 h = __float2bfloat16(x);
    return *reinterpret_cast<ushort*>(&h);
}
__device__ __forceinline__ float bf16_back(ushort u) {
    __hip_bfloat16 h = *reinterpret_cast<__hip_bfloat16*>(&u);
    return __bfloat162float(h);
}

// ---------------------------------------------------------------------------
// prep: (a) zero vpad pad rows [384 blocks], (b) values -> bf16 HI plane only
// [4096 blocks] (2-product split drops the A-residual product), (c/d) weights
// -> hi+lo planes [1024+1024 blocks] (B-side keeps its residual: w rounding
// would be a systematic error through the whole contraction).
__global__ __launch_bounds__(256) void prep(const float* __restrict__ values,
                                            const float* __restrict__ w_in,
                                            const float* __restrict__ w_out,
                                            ushort* __restrict__ Ph,
                                            ushort* __restrict__ Wh, ushort* __restrict__ Wl,
                                            ushort* __restrict__ W2h, ushort* __restrict__ W2l,
                                            float* __restrict__ vpad)
{
    int blk = blockIdx.x;
    if (blk < 384) {                               // zero the 4 pad regions
        const int r  = blk / 96;
        const int rr = blk % 96;
        const int b  = r >> 1;
        const int row0 = (r & 1) ? (LP - 96) : 0;
        size_t off = ((size_t)b * LP + row0 + rr) * D_MODEL + threadIdx.x * 4;
        *(float4*)(vpad + off) = make_float4(0.f, 0.f, 0.f, 0.f);
        return;
    }
    blk -= 384;
    if (blk < 4096) {                              // values -> hi plane only
        const size_t i = ((size_t)blk * 256 + threadIdx.x) * 4;
        float4 v = *(const float4*)(values + i);
        *(ushort4*)(Ph + i) = make_ushort4(bf16_hi(v.x), bf16_hi(v.y),
                                           bf16_hi(v.z), bf16_hi(v.w));
        return;
    }
    blk -= 4096;
    const float* src;
    ushort *oh, *ol;
    if (blk < 1024) { src = w_in;  oh = Wh;  ol = Wl;  }
    else            { src = w_out; oh = W2h; ol = W2l; blk -= 1024; }

    const size_t i = ((size_t)blk * 256 + threadIdx.x) * 4;
    float4 v = *(const float4*)(src + i);
    float f[4] = {v.x, v.y, v.z, v.w};
    ushort hb[4], lb[4];
    #pragma unroll
    for (int j = 0; j < 4; ++j) {
        hb[j] = bf16_hi(f[j]);
        lb[j] = bf16_hi(f[j] - bf16_back(hb[j]));
    }
    *(ushort4*)(oh + i) = make_ushort4(hb[0], hb[1], hb[2], hb[3]);
    *(ushort4*)(ol + i) = make_ushort4(lb[0], lb[1], lb[2], lb[3]);
}

// ---------------------------------------------------------------------------
// gemm2p: C[M,N] = Ah*(Bh+Bl)^T via 2 bf16 MFMA products, fp32 acc.
// (2-product split: A hi-plane only; dropped term = a_resid*b ~ 2^-9.8 rel.)
// M=4096, N=K=1024. Tile 128x128, BK=32, 512 threads = 8 waves (2m x 4n),
// wave-tile 64x32. R6 skeleton: 4-buf counted-vmcnt pipeline, 3 loads/tile,
// WAITBAR(6) steady state. Column-slab XCD swizzle (one n-panel per XCD ->
// B slice L2-resident). k-chunk XOR swizzle on global SOURCE + same
// involution on ds_read (SQ_LDS_BANK_CONFLICT verified 0).
// Per K-step/wave: 8 ds_read_b128, 16 MFMA (was 12/24 in 3-product).
// DO_PAD=1 remaps output row m -> vpad row (b*LP + (m&2047) + PADF).
template<int DO_PAD>
__global__ __launch_bounds__(512) void gemm2p(const ushort* __restrict__ Ah,
                                              const ushort* __restrict__ Bh,
                                              const ushort* __restrict__ Bl,
                                              float* __restrict__ C)
{
    // [buf][plane][128 rows * 32 k]  plane: 0=Ah 1=Bh 2=Bl
    __shared__ __align__(16) ushort lds[4][3][4096];

    const int tid = threadIdx.x;
    const int w   = tid >> 6;
    const int l   = tid & 63;

    const int bn  = (blockIdx.x & 7) * 128;          // one n-panel per XCD
    const int bm  = (blockIdx.x >> 3) * 128;         // 32 m-panels

    // --- staging: 512 threads x 16B = 8KB = one full plane per issue ---
    const int srow   = tid >> 2;                          // 0..127
    const int schunk = (tid & 3) ^ ((tid >> 3) & 3);      // pre-swizzled source chunk
    const ushort* gAh = Ah + (size_t)(bm + srow) * 1024 + schunk * 8;
    const ushort* gBh = Bh + (size_t)(bn + srow) * 1024 + schunk * 8;
    const ushort* gBl = Bl + (size_t)(bn + srow) * 1024 + schunk * 8;
    const int ldst = tid * 8;                             // linear LDS dest (ushort)

    // --- fragment read params ---
    const int fr  = l & 15;                // row within 16x16 fragment
    const int fq  = l >> 4;                // k-chunk 0..3
    const int swz = (fr >> 1) & 3;         // chunk XOR (matches source swizzle)
    const int rdo = (fq ^ swz) << 3;       // element offset of swizzled chunk
    const int wr  = w >> 2;                // 0..1 -> m offset wr*64
    const int wc  = w & 3;                 // 0..3 -> n offset wc*32

    f32x4 acc[4][2];
    #pragma unroll
    for (int mi = 0; mi < 4; ++mi)
        #pragma unroll
        for (int ni = 0; ni < 2; ++ni) acc[mi][ni] = (f32x4){0.f, 0.f, 0.f, 0.f};

    #define STAGE(buf, kt)                                        \
        do {                                                      \
            const size_t ko_ = (size_t)(kt) * 32;                 \
            gll16(gAh + ko_, &lds[(buf)][0][ldst]);               \
            gll16(gBh + ko_, &lds[(buf)][1][ldst]);               \
            gll16(gBl + ko_, &lds[(buf)][2][ldst]);               \
        } while (0)

    // WAITBAR(N): my tile-(kt) loads retired (N younger in flight), then
    // barrier -> ALL waves' tile-(kt) loads are in LDS.
    #define WAITBAR(N) asm volatile("s_waitcnt vmcnt(" #N ")\n\ts_barrier" ::: "memory")

    #define COMPUTE(cur)                                                                   \
        do {                                                                               \
            bf16x8 ah[4];                                                                  \
            _Pragma("unroll")                                                              \
            for (int mi = 0; mi < 4; ++mi) {                                               \
                const int row = wr * 64 + mi * 16 + fr;                                    \
                ah[mi] = *(const bf16x8*)&lds[(cur)][0][row * 32 + rdo];                   \
            }                                                                              \
            _Pragma("unroll")                                                              \
            for (int ni = 0; ni < 2; ++ni) {                                               \
                const int row = wc * 32 + ni * 16 + fr;                                    \
                bf16x8 bh = *(const bf16x8*)&lds[(cur)][1][row * 32 + rdo];                \
                bf16x8 bl = *(const bf16x8*)&lds[(cur)][2][row * 32 + rdo];                \
                _Pragma("unroll")                                                          \
                for (int mi = 0; mi < 4; ++mi)                                             \
                    acc[mi][ni] = __builtin_amdgcn_mfma_f32_16x16x32_bf16(ah[mi], bh, acc[mi][ni], 0, 0, 0); \
                _Pragma("unroll")                                                          \
                for (int mi = 0; mi < 4; ++mi)                                             \
                    acc[mi][ni] = __builtin_amdgcn_mfma_f32_16x16x32_bf16(ah[mi], bl, acc[mi][ni], 0, 0, 0); \
            }                                                                              \
        } while (0)

    STAGE(0, 0);
    STAGE(1, 1);
    STAGE(2, 2);

    for (int kt = 0; kt < 29; ++kt) {
        WAITBAR(6);
        STAGE((kt + 3) & 3, kt + 3);
        COMPUTE(kt & 3);
    }
    WAITBAR(6); COMPUTE(1);   // kt=29 (tiles 30,31 in flight)
    WAITBAR(3); COMPUTE(2);   // kt=30
    WAITBAR(0); COMPUTE(3);   // kt=31

    #undef STAGE
    #undef WAITBAR
    #undef COMPUTE

    // epilogue: C/D layout col=lane&15, row=(lane>>4)*4+reg  [m89/m91]
    #pragma unroll
    for (int mi = 0; mi < 4; ++mi) {
        #pragma unroll
        for (int ni = 0; ni < 2; ++ni) {
            const int col = bn + wc * 32 + ni * 16 + fr;
            #pragma unroll
            for (int j = 0; j < 4; ++j) {
                const int m = bm + wr * 64 + mi * 16 + fq * 4 + j;
                const size_t row = DO_PAD ? ((size_t)(m >> 11) * LP + (m & (L_SEQ - 1)) + PADF)
                                          : (size_t)m;
                C[row * 1024 + col] = acc[mi][ni][j];
            }
        }
    }
}

// ---------------------------------------------------------------------------
// gauss_conv_hi: att[b,q,d] = sum_{delta=-71..56} w[h][delta]*vpad[b,q+delta,d]
// (delta=-72 term <= 5e-16, dropped). Block = 64 d-cols x 128 q-rows; stages
// 256 rows x 64 floats (64KB) in LDS once; each thread owns one d-column and
// 32 q-accumulators, sliding a 47-register window per 16-delta chunk.
// Emits bf16 HI plane only (2-product split: gemm2's A-side residual dropped).
__global__ __launch_bounds__(256) void gauss_conv_hi(const float* __restrict__ vpad,
                                                     ushort* __restrict__ Oh)
{
    __shared__ __align__(16) float xs[256 * 64];   // [row][d] 64KB
    __shared__ float wt[128];                      // delta = j - 71

    const int tid = threadIdx.x;
    const int d0  = blockIdx.x * 64;
    const int q0  = blockIdx.y * 128;
    const int b   = blockIdx.z;
    const int h   = blockIdx.x >> 1;               // 64-wide d block => single head

    if (tid < 128) {
        const float sig = (float)(1 << (h & 3));   // std 1,2,4,8 ; offset = -std
        const float t = ((float)(tid - 71) + sig) / sig;
        wt[tid] = (0.39894228040143267794f / sig) * expf(-0.5f * t * t);
    }

    // stage rows [q0-71, q0+184] x [d0, d0+64)
    const float* src = vpad + ((size_t)b * LP + (PADF - 71) + q0) * 1024 + d0;
    #pragma unroll
    for (int p = 0; p < 16; ++p) {
        const int f   = p * 256 + tid;             // float4 index
        const int row = f >> 4;
        const int c4  = (f & 15) * 4;
        gll16(src + (size_t)row * 1024 + c4, &xs[f * 4]);
    }
    __syncthreads();

    const int d     = tid & 63;
    const int qbase = (tid >> 6) * 32;

    float acc[32];
    #pragma unroll
    for (int qq = 0; qq < 32; ++qq) acc[qq] = 0.f;

    #pragma unroll 1
    for (int c = 0; c < 8; ++c) {
        float xw[47];
        const float* xp = &xs[(qbase + c * 16) * 64 + d];
        #pragma unroll
        for (int j = 0; j < 47; ++j) xw[j] = xp[j * 64];
        #pragma unroll
        for (int dd = 0; dd < 16; ++dd) {
            const float wv = wt[c * 16 + dd];      // block-uniform broadcast
            #pragma unroll
            for (int qq = 0; qq < 32; ++qq)
                acc[qq] = fmaf(wv, xw[dd + qq], acc[qq]);
        }
    }

    ushort* oh = Oh + ((size_t)b * L_SEQ + q0 + qbase) * 1024 + d0 + d;
    #pragma unroll
    for (int qq = 0; qq < 32; ++qq)
        oh[(size_t)qq * 1024] = bf16_hi(acc[qq]);
}

// ---------------------------------------------------------------------------
extern "C" void kernel_launch(void* const* d_in, const int* in_sizes, int n_in,
                              void* d_out, int out_size, void* d_ws, size_t ws_size,
                              hipStream_t stream)
{
    const float* values = (const float*)d_in[0];   // [B,L,D]
    const float* w_in   = (const float*)d_in[1];   // [D,D]
    const float* w_out  = (const float*)d_in[2];   // [D,D]
    float* out = (float*)d_out;                    // [B,L,D]

    // workspace layout (~35 MB used)
    float*  vpad = (float*)d_ws;                                  // [B][LP][D] fp32
    ushort* Ph  = (ushort*)(vpad + (size_t)B_SZ * LP * D_MODEL);  // [4096][1024] bf16 hi
    ushort* Wh  = Ph  + (size_t)4096 * 1024;                      // w_in hi
    ushort* Wl  = Wh  + (size_t)1024 * 1024;                      // w_in lo
    ushort* W2h = Wl  + (size_t)1024 * 1024;                      // w_out hi
    ushort* W2l = W2h + (size_t)1024 * 1024;                      // w_out lo

    // 1) prep: zero pads + split (values -> hi only; weights -> hi+lo)
    prep<<<dim3(384 + 4096 + 1024 + 1024), dim3(256), 0, stream>>>(
        values, w_in, w_out, Ph, Wh, Wl, W2h, W2l, vpad);

    // 2) v = values_hi @ (w_in_hi + w_in_lo)^T  (into padded fp32 buffer)
    gemm2p<1><<<dim3(256), dim3(512), 0, stream>>>(Ph, Wh, Wl, vpad);

    // 3) Gaussian conv -> att hi plane (reuses Ph)
    dim3 cgrid(D_MODEL / 64, L_SEQ / 128, B_SZ);   // 16 x 16 x 2 = 512 blocks
    gauss_conv_hi<<<cgrid, dim3(256), 0, stream>>>(vpad, Ph);

    // 4) out = att_hi @ (w_out_hi + w_out_lo)^T
    gemm2p<0><<<dim3(256), dim3(512), 0, stream>>>(Ph, W2h, W2l, out);
}